// Round 1
// baseline (528.673 us; speedup 1.0000x reference)
//
#include <hip/hip_runtime.h>
#include <hip/hip_bf16.h>

// ConvMosaic: y[n,co,h,w] = sum_{ci,di,dj} x_pad[n,ci,h+di-1,w+dj-1] * W[w%16, ci*9+di*3+dj, co]
// x: [4,32,256,256] f32, W: [16,288,64] f32, y: [4,64,256,256] f32

constexpr int NB    = 4;
constexpr int C_IN  = 32;
constexpr int HH    = 256;
constexpr int WW    = 256;
constexpr int C_OUT = 64;
constexpr int TILE  = 16;
constexpr int XS    = TILE + 2;  // 18 (halo)

__global__ __launch_bounds__(256)
void conv_mosaic_f32(const float* __restrict__ x,
                     const float* __restrict__ wgt,
                     float* __restrict__ out) {
    __shared__ float xs[C_IN][XS][XS];  // 32*18*18*4 = 41472 B

    const int n  = blockIdx.y;
    const int th = blockIdx.x / (WW / TILE);
    const int tw = blockIdx.x % (WW / TILE);
    const int h0 = th * TILE;
    const int w0 = tw * TILE;
    const int t  = threadIdx.x;

    // ---- stage x tile (with zero-padded halo) into LDS ----
    const float* xn = x + (size_t)n * C_IN * HH * WW;
    for (int idx = t; idx < C_IN * XS * XS; idx += 256) {
        const int c  = idx / (XS * XS);
        const int r  = (idx / XS) % XS;
        const int cc = idx % XS;
        const int gh = h0 + r - 1;
        const int gw = w0 + cc - 1;
        float v = 0.0f;
        if (gh >= 0 && gh < HH && gw >= 0 && gw < WW)
            v = xn[((size_t)c * HH + gh) * WW + gw];
        xs[c][r][cc] = v;
    }
    __syncthreads();

    // thread -> (w_local, h-group of 4 rows, c_out-group of 16)
    const int wl = t & 15;        // == s, since w0 % 16 == 0
    const int hg = (t >> 4) & 3;
    const int cg = t >> 6;

    // weight slice for this s and c_out group; float4 over c_out
    const float4* wp4 =
        reinterpret_cast<const float4*>(wgt + (size_t)wl * 288 * 64 + cg * 16);
    // wp4[k*16 + j4] = W[s][k][cg*16 + j4*4 .. +3]

    float acc[4][16];
#pragma unroll
    for (int a = 0; a < 4; ++a)
#pragma unroll
        for (int b = 0; b < 16; ++b) acc[a][b] = 0.0f;

    for (int c = 0; c < C_IN; ++c) {
#pragma unroll
        for (int di = 0; di < 3; ++di) {
#pragma unroll
            for (int dj = 0; dj < 3; ++dj) {
                const int k = c * 9 + di * 3 + dj;
                float4 wv0 = wp4[k * 16 + 0];
                float4 wv1 = wp4[k * 16 + 1];
                float4 wv2 = wp4[k * 16 + 2];
                float4 wv3 = wp4[k * 16 + 3];
#pragma unroll
                for (int hh = 0; hh < 4; ++hh) {
                    const float xv = xs[c][hg * 4 + hh + di][wl + dj];
                    acc[hh][0]  += xv * wv0.x;
                    acc[hh][1]  += xv * wv0.y;
                    acc[hh][2]  += xv * wv0.z;
                    acc[hh][3]  += xv * wv0.w;
                    acc[hh][4]  += xv * wv1.x;
                    acc[hh][5]  += xv * wv1.y;
                    acc[hh][6]  += xv * wv1.z;
                    acc[hh][7]  += xv * wv1.w;
                    acc[hh][8]  += xv * wv2.x;
                    acc[hh][9]  += xv * wv2.y;
                    acc[hh][10] += xv * wv2.z;
                    acc[hh][11] += xv * wv2.w;
                    acc[hh][12] += xv * wv3.x;
                    acc[hh][13] += xv * wv3.y;
                    acc[hh][14] += xv * wv3.z;
                    acc[hh][15] += xv * wv3.w;
                }
            }
        }
    }

    // ---- store ----
#pragma unroll
    for (int hh = 0; hh < 4; ++hh) {
        const int h = h0 + hg * 4 + hh;
#pragma unroll
        for (int j = 0; j < 16; ++j) {
            const int co = cg * 16 + j;
            out[(((size_t)n * C_OUT + co) * HH + h) * WW + w0 + wl] = acc[hh][j];
        }
    }
}

extern "C" void kernel_launch(void* const* d_in, const int* in_sizes, int n_in,
                              void* d_out, int out_size, void* d_ws, size_t ws_size,
                              hipStream_t stream) {
    const float* x = (const float*)d_in[0];
    const float* w = (const float*)d_in[1];
    float* out     = (float*)d_out;

    dim3 grid((HH / TILE) * (WW / TILE), NB);  // 256 x 4 = 1024 blocks
    conv_mosaic_f32<<<grid, 256, 0, stream>>>(x, w, out);
}

// Round 2
// 109.093 us; speedup vs baseline: 4.8461x; 4.8461x over previous
//
#include <hip/hip_runtime.h>
#include <hip/hip_bf16.h>

// ConvMosaic via bf16 MFMA.
// y[n,co,h,w] = sum_{c,di,dj} x[n,c,h+di-1,w+dj-1] * W[w%16, c*9+di*3+dj, co]
// K reordered as k' = tap*32 + c (tap = di*3+dj) so one MFMA K=32 step == one tap.

using bf16 = __hip_bfloat16;
typedef __attribute__((ext_vector_type(8))) short bf16x8_t;  // A/B frag: 8 bf16 (4 VGPR)
typedef __attribute__((ext_vector_type(4))) float f32x4_t;   // C/D frag

constexpr int NB    = 4;
constexpr int C_IN  = 32;
constexpr int HH    = 256;
constexpr int WW    = 256;
constexpr int C_OUT = 64;
constexpr int SPE   = 16;

constexpr int TH = 16;          // tile height (== MFMA M)
constexpr int TW = 32;          // tile width (w and w+16 share s = w%16)
constexpr int XR = TH + 2;      // 18
constexpr int XC = TW + 2;      // 34
constexpr int CPAD = 40;        // c-dim padded 32->40: row stride 80 B (16B-aligned, banks spread)

// ---- pre-pass: W[s][c*9+tap][co] f32 -> W_t[s][co][tap*32+c] bf16 ----
__global__ __launch_bounds__(256)
void prep_weights(const float* __restrict__ w, bf16* __restrict__ wt) {
    int idx = blockIdx.x * 256 + threadIdx.x;  // 16*64*288 total
    if (idx >= SPE * C_OUT * 288) return;
    int s  = idx / (C_OUT * 288);
    int r  = idx % (C_OUT * 288);
    int co = r / 288;
    int kk = r % 288;            // kk = tap*32 + c
    int tap = kk >> 5;
    int c   = kk & 31;
    float v = w[((size_t)s * 288 + c * 9 + tap) * C_OUT + co];
    wt[idx] = __float2bfloat16(v);
}

__global__ __launch_bounds__(256)
void conv_mosaic_mfma(const float* __restrict__ x,
                      const bf16* __restrict__ wt,
                      float* __restrict__ out) {
    __shared__ __align__(16) bf16 xs[XR * XC * CPAD];  // 18*34*40*2 = 48960 B

    const int n  = blockIdx.y;
    const int tw = blockIdx.x & 7;    // 8 w-tiles
    const int th = blockIdx.x >> 3;   // 16 h-tiles
    const int h0 = th * TH;
    const int w0 = tw * TW;
    const int t  = threadIdx.x;

    // ---- stage x tile (zero-padded halo), f32 -> bf16, layout [row][col][c] ----
    const float* xn = x + (size_t)n * C_IN * HH * WW;
    for (int idx = t; idx < C_IN * XR * XC; idx += 256) {
        int c   = idx / (XR * XC);
        int rr  = idx % (XR * XC);
        int r   = rr / XC;
        int col = rr % XC;
        int gh = h0 + r - 1;
        int gw = w0 + col - 1;
        float v = 0.0f;
        if (gh >= 0 && gh < HH && gw >= 0 && gw < WW)
            v = xn[((size_t)c * HH + gh) * WW + gw];
        xs[(r * XC + col) * CPAD + c] = __float2bfloat16(v);
    }
    __syncthreads();

    const int wave = t >> 6;     // 4 waves: wave handles s = wave*4 .. wave*4+3
    const int lane = t & 63;
    const int lm   = lane & 15;  // A: row m (h). B: col n (co). D: col n (co).
    const int lg   = lane >> 4;  // k-group: k_local = 8*lg + v

    for (int si = 0; si < 4; ++si) {
        const int s = wave * 4 + si;

        // A fragments for this s: 9 taps x 2 w-halves, held in registers (72 VGPR)
        bf16x8_t afr[2][9];
#pragma unroll
        for (int wm = 0; wm < 2; ++wm)
#pragma unroll
            for (int tap = 0; tap < 9; ++tap) {
                const int di = tap / 3, dj = tap % 3;
                const int r   = lm + di;
                const int col = s + wm * 16 + dj;
                afr[wm][tap] = *reinterpret_cast<const bf16x8_t*>(
                    &xs[(r * XC + col) * CPAD + lg * 8]);
            }

#pragma unroll
        for (int ct = 0; ct < 4; ++ct) {
            // B frag base: W_t[s][ct*16+lm][tap*32 + 8*lg]
            const bf16* bp = wt + ((size_t)(s * C_OUT + ct * 16 + lm) * 288 + lg * 8);
            f32x4_t acc0 = {0.f, 0.f, 0.f, 0.f};
            f32x4_t acc1 = {0.f, 0.f, 0.f, 0.f};
#pragma unroll
            for (int tap = 0; tap < 9; ++tap) {
                bf16x8_t bfr = *reinterpret_cast<const bf16x8_t*>(bp + tap * 32);
                acc0 = __builtin_amdgcn_mfma_f32_16x16x32_bf16(afr[0][tap], bfr, acc0, 0, 0, 0);
                acc1 = __builtin_amdgcn_mfma_f32_16x16x32_bf16(afr[1][tap], bfr, acc1, 0, 0, 0);
            }
            // D: row(h) = 4*lg + j, col(co) = lm
            const int co = ct * 16 + lm;
#pragma unroll
            for (int j = 0; j < 4; ++j) {
                const int h = h0 + lg * 4 + j;
                size_t base = (((size_t)n * C_OUT + co) * HH + h) * WW + w0 + s;
                out[base]      = acc0[j];
                out[base + 16] = acc1[j];
            }
        }
    }
}

extern "C" void kernel_launch(void* const* d_in, const int* in_sizes, int n_in,
                              void* d_out, int out_size, void* d_ws, size_t ws_size,
                              hipStream_t stream) {
    const float* x = (const float*)d_in[0];
    const float* w = (const float*)d_in[1];
    float* out     = (float*)d_out;
    bf16* wt       = (bf16*)d_ws;   // needs 16*64*288*2 = 589824 B

    // weight repack+cast
    prep_weights<<<(SPE * C_OUT * 288 + 255) / 256, 256, 0, stream>>>(w, wt);

    dim3 grid((WW / TW) * (HH / TH), NB);  // (8*16, 4) = 512 blocks
    conv_mosaic_mfma<<<grid, 256, 0, stream>>>(x, wt, out);
}

// Round 3
// 75.522 us; speedup vs baseline: 7.0002x; 1.4445x over previous
//
#include <hip/hip_runtime.h>
#include <hip/hip_bf16.h>

// ConvMosaic via bf16 MFMA.
// y[n,co,h,w] = sum_{c,di,dj} x[n,c,h+di-1,w+dj-1] * W[w%16, c*9+di*3+dj, co]
// K reordered as k' = tap*32 + c (tap = di*3+dj) so one MFMA K=32 step == one tap.

using bf16 = __hip_bfloat16;
typedef __attribute__((ext_vector_type(8))) short bf16x8_t;  // A/B frag: 8 bf16 (4 VGPR)
typedef __attribute__((ext_vector_type(4))) float f32x4_t;   // C/D frag

constexpr int NB    = 4;
constexpr int C_IN  = 32;
constexpr int HH    = 256;
constexpr int WW    = 256;
constexpr int C_OUT = 64;
constexpr int SPE   = 16;

constexpr int TH = 16;          // tile height (== MFMA M)
constexpr int TW = 32;          // tile width (w and w+16 share s = w%16)
constexpr int XR = TH + 2;      // 18
constexpr int XC = TW + 2;      // 34
constexpr int CPAD = 40;        // c-dim padded 32->40: 80 B row stride (16B-aligned)

// ---- pre-pass: W[s][c*9+tap][co] f32 -> W_t[s][co][tap*32+c] bf16 ----
__global__ __launch_bounds__(256)
void prep_weights(const float* __restrict__ w, bf16* __restrict__ wt) {
    int idx = blockIdx.x * 256 + threadIdx.x;  // 16*64*288 total
    if (idx >= SPE * C_OUT * 288) return;
    int s  = idx / (C_OUT * 288);
    int r  = idx % (C_OUT * 288);
    int co = r / 288;
    int kk = r % 288;            // kk = tap*32 + c
    int tap = kk >> 5;
    int c   = kk & 31;
    float v = w[((size_t)s * 288 + c * 9 + tap) * C_OUT + co];
    wt[idx] = __float2bfloat16(v);
}

__global__ __launch_bounds__(512, 4)
void conv_mosaic_mfma(const float* __restrict__ x,
                      const bf16* __restrict__ wt,
                      float* __restrict__ out) {
    __shared__ __align__(16) bf16 xs[XR * XC * CPAD];  // 18*34*40*2 = 48960 B

    const int n  = blockIdx.y;
    const int tw = blockIdx.x & 7;    // 8 w-tiles
    const int th = blockIdx.x >> 3;   // 16 h-tiles
    const int h0 = th * TH;
    const int w0 = tw * TW;
    const int t  = threadIdx.x;

    // ---- stage x tile (zero-padded halo), f32 -> bf16, layout [row][col][c] ----
    const float* xn = x + (size_t)n * C_IN * HH * WW;
    for (int idx = t; idx < C_IN * XR * XC; idx += 512) {
        int c   = idx / (XR * XC);
        int rr  = idx % (XR * XC);
        int r   = rr / XC;
        int col = rr % XC;
        int gh = h0 + r - 1;
        int gw = w0 + col - 1;
        float v = 0.0f;
        if (gh >= 0 && gh < HH && gw >= 0 && gw < WW)
            v = xn[((size_t)c * HH + gh) * WW + gw];
        xs[(r * XC + col) * CPAD + c] = __float2bfloat16(v);
    }
    __syncthreads();

    // 8 waves: wave = s-group (wave&3) x ct-half (wave>>2)
    const int wave = t >> 6;
    const int lane = t & 63;
    const int g    = wave & 3;    // s = g*4 + si
    const int cth  = wave >> 2;   // ct = cth*2 + ctl
    const int lm   = lane & 15;   // A: row m (h). B/D: col n (co).
    const int lg   = lane >> 4;   // k-group; D row group

    // persistent accumulators: [ctl][wm][si], si packs 4 consecutive w
    f32x4_t dacc[2][2][4];
#pragma unroll
    for (int a = 0; a < 2; ++a)
#pragma unroll
        for (int b = 0; b < 2; ++b)
#pragma unroll
            for (int c = 0; c < 4; ++c) dacc[a][b][c] = (f32x4_t){0.f, 0.f, 0.f, 0.f};

#pragma unroll
    for (int si = 0; si < 4; ++si) {
        const int s = g * 4 + si;
#pragma unroll
        for (int wm = 0; wm < 2; ++wm) {
            // A fragments for this (s, w-half): 9 taps
            bf16x8_t afr[9];
#pragma unroll
            for (int tap = 0; tap < 9; ++tap) {
                const int di = tap / 3, dj = tap % 3;
                afr[tap] = *reinterpret_cast<const bf16x8_t*>(
                    &xs[((lm + di) * XC + s + wm * 16 + dj) * CPAD + lg * 8]);
            }
#pragma unroll
            for (int ctl = 0; ctl < 2; ++ctl) {
                const int ct = cth * 2 + ctl;
                const bf16* bp =
                    wt + ((size_t)(s * C_OUT + ct * 16 + lm) * 288 + lg * 8);
#pragma unroll
                for (int tap = 0; tap < 9; ++tap) {
                    bf16x8_t bfr = *reinterpret_cast<const bf16x8_t*>(bp + tap * 32);
                    dacc[ctl][wm][si] = __builtin_amdgcn_mfma_f32_16x16x32_bf16(
                        afr[tap], bfr, dacc[ctl][wm][si], 0, 0, 0);
                }
            }
        }
    }

    // ---- store: float4 across si (4 consecutive w) ----
#pragma unroll
    for (int ctl = 0; ctl < 2; ++ctl) {
        const int co = (cth * 2 + ctl) * 16 + lm;
#pragma unroll
        for (int wm = 0; wm < 2; ++wm) {
#pragma unroll
            for (int j = 0; j < 4; ++j) {
                const int h = h0 + lg * 4 + j;
                float4 v = make_float4(dacc[ctl][wm][0][j], dacc[ctl][wm][1][j],
                                       dacc[ctl][wm][2][j], dacc[ctl][wm][3][j]);
                *reinterpret_cast<float4*>(
                    &out[(((size_t)n * C_OUT + co) * HH + h) * WW + w0 + g * 4 + wm * 16]) = v;
            }
        }
    }
}

extern "C" void kernel_launch(void* const* d_in, const int* in_sizes, int n_in,
                              void* d_out, int out_size, void* d_ws, size_t ws_size,
                              hipStream_t stream) {
    const float* x = (const float*)d_in[0];
    const float* w = (const float*)d_in[1];
    float* out     = (float*)d_out;
    bf16* wt       = (bf16*)d_ws;   // needs 16*64*288*2 = 589824 B

    prep_weights<<<(SPE * C_OUT * 288 + 255) / 256, 256, 0, stream>>>(w, wt);

    dim3 grid((WW / TW) * (HH / TH), NB);  // (8*16, 4) = 512 blocks
    conv_mosaic_mfma<<<grid, 512, 0, stream>>>(x, wt, out);
}

// Round 4
// 64.466 us; speedup vs baseline: 8.2008x; 1.1715x over previous
//
#include <hip/hip_runtime.h>
#include <hip/hip_bf16.h>

// ConvMosaic via bf16 MFMA.
// y[n,co,h,w] = sum_{c,di,dj} x[n,c,h+di-1,w+dj-1] * W[w%16, c*9+di*3+dj, co]
// K reordered as k' = tap*32 + c (tap = di*3+dj) so one MFMA K=32 step == one tap.

using bf16 = __hip_bfloat16;
typedef __attribute__((ext_vector_type(8))) short bf16x8_t;  // A/B frag: 8 bf16 (4 VGPR)
typedef __attribute__((ext_vector_type(4))) float f32x4_t;   // C/D frag

constexpr int NB    = 4;
constexpr int C_IN  = 32;
constexpr int HH    = 256;
constexpr int WW    = 256;
constexpr int C_OUT = 64;
constexpr int SPE   = 16;

constexpr int TH = 16;          // tile height (== MFMA M)
constexpr int TW = 32;          // tile width (w and w+16 share s = w%16)
constexpr int XR = TH + 2;      // 18
constexpr int XC = TW + 2;      // 34
constexpr int CPAD = 40;        // c-dim padded 32->40: 80 B row stride (16B-aligned)

// ---- pre-pass: W[s][c*9+tap][co] f32 -> W_t[s][co][tap*32+c] bf16 ----
__global__ __launch_bounds__(256)
void prep_weights(const float* __restrict__ w, bf16* __restrict__ wt) {
    int idx = blockIdx.x * 256 + threadIdx.x;  // 16*64*288 total
    if (idx >= SPE * C_OUT * 288) return;
    int s  = idx / (C_OUT * 288);
    int r  = idx % (C_OUT * 288);
    int co = r / 288;
    int kk = r % 288;            // kk = tap*32 + c
    int tap = kk >> 5;
    int c   = kk & 31;
    float v = w[((size_t)s * 288 + c * 9 + tap) * C_OUT + co];
    wt[idx] = __float2bfloat16(v);
}

__global__ __launch_bounds__(1024, 8)
void conv_mosaic_mfma(const float* __restrict__ x,
                      const bf16* __restrict__ wt,
                      float* __restrict__ out) {
    __shared__ __align__(16) bf16 xs[XR * XC * CPAD];  // 18*34*40*2 = 48960 B

    const int n  = blockIdx.y;
    const int tw = blockIdx.x & 7;    // 8 w-tiles
    const int th = blockIdx.x >> 3;   // 16 h-tiles
    const int h0 = th * TH;
    const int w0 = tw * TW;
    const int t  = threadIdx.x;

    // ---- stage x tile (zero-padded halo), f32 -> bf16, layout [row][col][c] ----
    const float* xn = x + (size_t)n * C_IN * HH * WW;
    for (int idx = t; idx < C_IN * XR * XC; idx += 1024) {
        int c   = idx / (XR * XC);
        int rr  = idx % (XR * XC);
        int r   = rr / XC;
        int col = rr % XC;
        int gh = h0 + r - 1;
        int gw = w0 + col - 1;
        float v = 0.0f;
        if (gh >= 0 && gh < HH && gw >= 0 && gw < WW)
            v = xn[((size_t)c * HH + gh) * WW + gw];
        xs[(r * XC + col) * CPAD + c] = __float2bfloat16(v);
    }
    __syncthreads();

    // 16 waves: wave = s-group (wave&3) x c_out tile (wave>>2)
    const int wave = t >> 6;
    const int lane = t & 63;
    const int g    = wave & 3;    // s = g*4 + si
    const int ct   = wave >> 2;   // co tile: co = ct*16 + lm
    const int lm   = lane & 15;   // A: row m (h). B/D: col n (co).
    const int lg   = lane >> 4;   // k-group; D row group

    // persistent accumulators: [wm][si], si packs 4 consecutive w
    f32x4_t dacc[2][4];
#pragma unroll
    for (int b = 0; b < 2; ++b)
#pragma unroll
        for (int c = 0; c < 4; ++c) dacc[b][c] = (f32x4_t){0.f, 0.f, 0.f, 0.f};

#pragma unroll
    for (int si = 0; si < 4; ++si) {
        const int s = g * 4 + si;
        // B frag base: W_t[s][ct*16+lm][tap*32 + 8*lg]
        const bf16* bp = wt + ((size_t)(s * C_OUT + ct * 16 + lm) * 288 + lg * 8);
        const bf16* ap = &xs[(lm * XC + s) * CPAD + lg * 8];
#pragma unroll
        for (int tap = 0; tap < 9; ++tap) {
            const int di = tap / 3, dj = tap % 3;
            bf16x8_t bfr = *reinterpret_cast<const bf16x8_t*>(bp + tap * 32);
            bf16x8_t a0 = *reinterpret_cast<const bf16x8_t*>(ap + (di * XC + dj) * CPAD);
            bf16x8_t a1 = *reinterpret_cast<const bf16x8_t*>(ap + (di * XC + dj + 16) * CPAD);
            dacc[0][si] = __builtin_amdgcn_mfma_f32_16x16x32_bf16(a0, bfr, dacc[0][si], 0, 0, 0);
            dacc[1][si] = __builtin_amdgcn_mfma_f32_16x16x32_bf16(a1, bfr, dacc[1][si], 0, 0, 0);
        }
    }

    // ---- store: float4 across si (4 consecutive w) ----
    const int co = ct * 16 + lm;
#pragma unroll
    for (int wm = 0; wm < 2; ++wm) {
#pragma unroll
        for (int j = 0; j < 4; ++j) {
            const int h = h0 + lg * 4 + j;
            float4 v = make_float4(dacc[wm][0][j], dacc[wm][1][j],
                                   dacc[wm][2][j], dacc[wm][3][j]);
            *reinterpret_cast<float4*>(
                &out[(((size_t)n * C_OUT + co) * HH + h) * WW + w0 + g * 4 + wm * 16]) = v;
        }
    }
}

extern "C" void kernel_launch(void* const* d_in, const int* in_sizes, int n_in,
                              void* d_out, int out_size, void* d_ws, size_t ws_size,
                              hipStream_t stream) {
    const float* x = (const float*)d_in[0];
    const float* w = (const float*)d_in[1];
    float* out     = (float*)d_out;
    bf16* wt       = (bf16*)d_ws;   // needs 16*64*288*2 = 589824 B

    prep_weights<<<(SPE * C_OUT * 288 + 255) / 256, 256, 0, stream>>>(w, wt);

    dim3 grid((WW / TW) * (HH / TH), NB);  // (8*16, 4) = 512 blocks
    conv_mosaic_mfma<<<grid, 1024, 0, stream>>>(x, wt, out);
}

// Round 5
// 62.533 us; speedup vs baseline: 8.4544x; 1.0309x over previous
//
#include <hip/hip_runtime.h>
#include <hip/hip_bf16.h>

// ConvMosaic via bf16 MFMA.
// y[n,co,h,w] = sum_{c,di,dj} x[n,c,h+di-1,w+dj-1] * W[w%16, c*9+di*3+dj, co]
// K reordered as k' = tap*32 + c (tap = di*3+dj) so one MFMA K=32 step == one tap.

using bf16 = __hip_bfloat16;
typedef __attribute__((ext_vector_type(8))) short bf16x8_t;  // A/B frag: 8 bf16 (4 VGPR)
typedef __attribute__((ext_vector_type(4))) float f32x4_t;   // C/D frag

constexpr int NB    = 4;
constexpr int C_IN  = 32;
constexpr int HH    = 256;
constexpr int WW    = 256;
constexpr int C_OUT = 64;
constexpr int SPE   = 16;

constexpr int TH = 16;          // tile height (== MFMA M)
constexpr int TW = 32;          // tile width (w and w+16 share s = w%16)
constexpr int XR = TH + 2;      // 18
constexpr int XC = TW + 2;      // 34
constexpr int CPAD = 40;        // c-dim padded 32->40: 80 B row stride (16B-aligned)

// ---- pre-pass: W[s][c*9+tap][co] f32 -> W_t[s][co][tap*32+c] bf16 ----
__global__ __launch_bounds__(256)
void prep_weights(const float* __restrict__ w, bf16* __restrict__ wt) {
    int idx = blockIdx.x * 256 + threadIdx.x;  // 16*64*288 total
    if (idx >= SPE * C_OUT * 288) return;
    int s  = idx / (C_OUT * 288);
    int r  = idx % (C_OUT * 288);
    int co = r / 288;
    int kk = r % 288;            // kk = tap*32 + c
    int tap = kk >> 5;
    int c   = kk & 31;
    float v = w[((size_t)s * 288 + c * 9 + tap) * C_OUT + co];
    wt[idx] = __float2bfloat16(v);
}

__global__ __launch_bounds__(1024, 4)
void conv_mosaic_mfma(const float* __restrict__ x,
                      const bf16* __restrict__ wt,
                      float* __restrict__ out) {
    __shared__ __align__(16) bf16 xs[XR * XC * CPAD];  // 18*34*40*2 = 48960 B

    const int n  = blockIdx.y;
    const int tw = blockIdx.x & 7;    // 8 w-tiles
    const int th = blockIdx.x >> 3;   // 16 h-tiles
    const int h0 = th * TH;
    const int w0 = tw * TW;
    const int t  = threadIdx.x;

    // ---- stage x tile (zero-padded halo), f32 -> bf16, layout [row][col][c] ----
    // Interior cols 1..32: float4 loads (gw = w0 + q*4, 16B-aligned), fully unrolled
    // so all global loads are issued in a batch (latency overlap).
    const float* xn = x + (size_t)n * C_IN * HH * WW;
    constexpr int VJOBS = C_IN * XR * 8;  // 4608
#pragma unroll
    for (int it = 0; it < 5; ++it) {
        const int idx = t + it * 1024;
        if (idx < VJOBS) {
            const int c  = idx / (XR * 8);
            const int rr = idx % (XR * 8);
            const int r  = rr >> 3;
            const int q  = rr & 7;
            const int gh = h0 + r - 1;
            float4 v = make_float4(0.f, 0.f, 0.f, 0.f);
            if (gh >= 0 && gh < HH)
                v = *reinterpret_cast<const float4*>(
                    &xn[((size_t)c * HH + gh) * WW + w0 + q * 4]);
            bf16* d = &xs[(r * XC + q * 4 + 1) * CPAD + c];
            d[0]        = __float2bfloat16(v.x);
            d[CPAD]     = __float2bfloat16(v.y);
            d[2 * CPAD] = __float2bfloat16(v.z);
            d[3 * CPAD] = __float2bfloat16(v.w);
        }
    }
    // halo edge cols 0 and 33 (scalar, bounds-checked in h and w)
    constexpr int EJOBS = C_IN * XR * 2;  // 1152
#pragma unroll
    for (int it = 0; it < 2; ++it) {
        const int idx = t + it * 1024;
        if (idx < EJOBS) {
            const int c   = idx / (XR * 2);
            const int rr  = idx % (XR * 2);
            const int r   = rr >> 1;
            const int e   = rr & 1;
            const int col = e ? 33 : 0;
            const int gh  = h0 + r - 1;
            const int gw  = w0 + (e ? 32 : -1);
            float vv = 0.f;
            if (gh >= 0 && gh < HH && gw >= 0 && gw < WW)
                vv = xn[((size_t)c * HH + gh) * WW + gw];
            xs[(r * XC + col) * CPAD + c] = __float2bfloat16(vv);
        }
    }
    __syncthreads();

    // 16 waves: wave = s-group (wave&3) x c_out tile (wave>>2)
    const int wave = t >> 6;
    const int lane = t & 63;
    const int g    = wave & 3;    // s = g*4 + si
    const int ct   = wave >> 2;   // co tile: co = ct*16 + lm
    const int lm   = lane & 15;   // A: row m (h). B/D: col n (co).
    const int lg   = lane >> 4;   // k-group; D row group

    // persistent accumulators: [wm][si], si packs 4 consecutive w
    f32x4_t dacc[2][4];
#pragma unroll
    for (int b = 0; b < 2; ++b)
#pragma unroll
        for (int c = 0; c < 4; ++c) dacc[b][c] = (f32x4_t){0.f, 0.f, 0.f, 0.f};

#pragma unroll
    for (int si = 0; si < 4; ++si) {
        const int s = g * 4 + si;
        // prefetch all 9 B fragments for this si (batched global loads, L2-hot)
        const bf16* bp = wt + ((size_t)(s * C_OUT + ct * 16 + lm) * 288 + lg * 8);
        bf16x8_t bfr[9];
#pragma unroll
        for (int tap = 0; tap < 9; ++tap)
            bfr[tap] = *reinterpret_cast<const bf16x8_t*>(bp + tap * 32);

        const bf16* ap = &xs[(lm * XC + s) * CPAD + lg * 8];
#pragma unroll
        for (int tap = 0; tap < 9; ++tap) {
            const int di = tap / 3, dj = tap % 3;
            bf16x8_t a0 = *reinterpret_cast<const bf16x8_t*>(ap + (di * XC + dj) * CPAD);
            bf16x8_t a1 = *reinterpret_cast<const bf16x8_t*>(ap + (di * XC + dj + 16) * CPAD);
            dacc[0][si] = __builtin_amdgcn_mfma_f32_16x16x32_bf16(a0, bfr[tap], dacc[0][si], 0, 0, 0);
            dacc[1][si] = __builtin_amdgcn_mfma_f32_16x16x32_bf16(a1, bfr[tap], dacc[1][si], 0, 0, 0);
        }
    }

    // ---- store: float4 across si (4 consecutive w) ----
    const int co = ct * 16 + lm;
#pragma unroll
    for (int wm = 0; wm < 2; ++wm) {
#pragma unroll
        for (int j = 0; j < 4; ++j) {
            const int h = h0 + lg * 4 + j;
            float4 v = make_float4(dacc[wm][0][j], dacc[wm][1][j],
                                   dacc[wm][2][j], dacc[wm][3][j]);
            *reinterpret_cast<float4*>(
                &out[(((size_t)n * C_OUT + co) * HH + h) * WW + w0 + g * 4 + wm * 16]) = v;
        }
    }
}

extern "C" void kernel_launch(void* const* d_in, const int* in_sizes, int n_in,
                              void* d_out, int out_size, void* d_ws, size_t ws_size,
                              hipStream_t stream) {
    const float* x = (const float*)d_in[0];
    const float* w = (const float*)d_in[1];
    float* out     = (float*)d_out;
    bf16* wt       = (bf16*)d_ws;   // needs 16*64*288*2 = 589824 B

    prep_weights<<<(SPE * C_OUT * 288 + 255) / 256, 256, 0, stream>>>(w, wt);

    dim3 grid((WW / TW) * (HH / TH), NB);  // (8*16, 4) = 512 blocks
    conv_mosaic_mfma<<<grid, 1024, 0, stream>>>(x, wt, out);
}